// Round 7
// baseline (249.117 us; speedup 1.0000x reference)
//
#include <hip/hip_runtime.h>
#include <cmath>
#include <utility>

#define WIN 11
#define HALO 5
#define IMG 512
#define TW 64
#define TH 16
#define RH (TH + 2*HALO)
#define SH2 72
#define NIMG 48
#define NPIX (16.0 * 3.0 * 512.0 * 512.0)
#define CPR (IMG/2)          /* 256 col-pairs per row */

typedef _Float16 f16;
typedef _Float16 h2 __attribute__((ext_vector_type(2)));

struct GaussW { float w[WIN]; };

__device__ __forceinline__ unsigned pk2(float a, float b) {
    auto h = __builtin_amdgcn_cvt_pkrtz(a, b);   // __fp16 ext_vector(2)
    return __builtin_bit_cast(unsigned, h);
}
__device__ __forceinline__ h2 uph(unsigned u) {
    return __builtin_bit_cast(h2, u);
}

__global__ void __launch_bounds__(64) zero_kernel(float* out) {
    if (threadIdx.x == 0) out[0] = 0.f;
}

__global__ void __launch_bounds__(64) finish_kernel(float* out) {
    if (threadIdx.x == 0)
        out[0] = 1.0f - out[0] * (float)(1.0 / NPIX);
}

// ---------------- K1: horizontal blur -> interleaved f16 workspace ----------
// wsA[(lz*IMG + row)*CPR + cp] = uint4{ pk(x), pk(y), pk(xx), pk(yy) }
// wsB[(lz*IMG + row)*CPR + cp] = pk(xy)
// One wave = one image row (64 col-groups of 8). No LDS, no barrier.
__global__ void __launch_bounds__(256, 1) k1_hblur(
        const float* __restrict__ xin, const float* __restrict__ yin,
        uint4* __restrict__ wsA, unsigned* __restrict__ wsB,
        int imgOff, GaussW W) {
    const int tid = threadIdx.x;
    const int c   = tid & 63;                    // out cols 8c..8c+7
    const int row = blockIdx.y * 4 + (tid >> 6);
    const int lz  = blockIdx.z;
    const size_t rbase = ((size_t)(imgOff + lz) * IMG + row) * IMG;
    const float* xr = xin + rbase;
    const float* yr = yin + rbase;
    const int gx0 = c * 8 - 5;                   // window cols gx0..gx0+17

    float xv[18], yv[18];
    if (c >= 1 && c <= 62) {
        // gx0+1 = 8c-4 is 4-aligned: aligned float4 runs cover [gx0+1, gx0+16]
        xv[0] = xr[gx0];  yv[0] = yr[gx0];
        #pragma unroll
        for (int q = 0; q < 4; ++q) {
            float4 a = *(const float4*)(xr + gx0 + 1 + 4*q);
            float4 b = *(const float4*)(yr + gx0 + 1 + 4*q);
            xv[1+4*q] = a.x; xv[2+4*q] = a.y; xv[3+4*q] = a.z; xv[4+4*q] = a.w;
            yv[1+4*q] = b.x; yv[2+4*q] = b.y; yv[3+4*q] = b.z; yv[4+4*q] = b.w;
        }
        xv[17] = xr[gx0 + 17];  yv[17] = yr[gx0 + 17];
    } else {
        #pragma unroll
        for (int j = 0; j < 18; ++j) {
            int gx = gx0 + j;
            bool ok = ((unsigned)gx < IMG);
            xv[j] = ok ? xr[gx] : 0.f;
            yv[j] = ok ? yr[gx] : 0.f;
        }
    }

    float ax[8]  = {0,0,0,0,0,0,0,0}, ay[8]  = {0,0,0,0,0,0,0,0};
    float axx[8] = {0,0,0,0,0,0,0,0}, ayy[8] = {0,0,0,0,0,0,0,0};
    float axy[8] = {0,0,0,0,0,0,0,0};
    #pragma unroll
    for (int j = 0; j < 18; ++j) {
        float xs = xv[j], ys = yv[j];
        float xx = xs * xs, yy = ys * ys, xy = xs * ys;
        #pragma unroll
        for (int o = 0; o < 8; ++o) {
            int k = j - o;
            if (k >= 0 && k < WIN) {
                float wk = W.w[k];
                ax[o]  += wk * xs;
                ay[o]  += wk * ys;
                axx[o] += wk * xx;
                ayy[o] += wk * yy;
                axy[o] += wk * xy;
            }
        }
    }

    const size_t ob = ((size_t)lz * IMG + row) * CPR + 4 * c;
    #pragma unroll
    for (int p = 0; p < 4; ++p) {
        uint4 u;
        u.x = pk2(ax [2*p], ax [2*p+1]);
        u.y = pk2(ay [2*p], ay [2*p+1]);
        u.z = pk2(axx[2*p], axx[2*p+1]);
        u.w = pk2(ayy[2*p], ayy[2*p+1]);
        wsA[ob + p] = u;
        wsB[ob + p] = pk2(axy[2*p], axy[2*p+1]);
    }
}

// ---------------- K2: vertical blur + SSIM + reduce -------------------------
// Thread owns one col-pair over a 16-row strip; 2 loads per row-step
// (uint4 = 4 fields + dword = 5th), next row prefetched. No LDS, no barrier.
__global__ void __launch_bounds__(256, 1) k2_vblur(
        const uint4* __restrict__ wsA, const unsigned* __restrict__ wsB,
        float* __restrict__ out_acc, GaussW W) {
    const int cp = threadIdx.x;                  // col-pair 0..255
    const int r0 = blockIdx.y * TH;
    const int lz = blockIdx.z;
    const size_t base = (size_t)lz * IMG * CPR + cp;

    h2 w2[WIN];
    #pragma unroll
    for (int k = 0; k < WIN; ++k) {
        f16 wk = (f16)W.w[k];
        w2[k] = (h2){wk, wk};
    }

    h2 acc[5][TH];
    #pragma unroll
    for (int f = 0; f < 5; ++f)
        #pragma unroll
        for (int o = 0; o < TH; ++o) acc[f][o] = (h2){(f16)0, (f16)0};

    auto run = [&](auto guard_c) {
        constexpr bool G = decltype(guard_c)::value;
        auto ld = [&](int j, uint4& a, unsigned& b) {
            int r = r0 - HALO + j;
            if (G && ((unsigned)r >= IMG)) {
                a = make_uint4(0u, 0u, 0u, 0u); b = 0u;
            } else {
                size_t ix = base + (size_t)r * CPR;
                a = wsA[ix];
                b = wsB[ix];
            }
        };
        uint4 ca; unsigned cb;
        ld(0, ca, cb);
        #pragma unroll
        for (int j = 0; j < TH + 2*HALO; ++j) {
            uint4 na; unsigned nb;
            if (j < TH + 2*HALO - 1) ld(j + 1, na, nb);
            h2 v0 = uph(ca.x), v1 = uph(ca.y), v2 = uph(ca.z),
               v3 = uph(ca.w), v4 = uph(cb);
            #pragma unroll
            for (int o = 0; o < TH; ++o) {
                int k = j - o;
                if (k >= 0 && k < WIN) {
                    acc[0][o] += w2[k] * v0;
                    acc[1][o] += w2[k] * v1;
                    acc[2][o] += w2[k] * v2;
                    acc[3][o] += w2[k] * v3;
                    acc[4][o] += w2[k] * v4;
                }
            }
            ca = na; cb = nb;
        }
    };
    if (blockIdx.y >= 1 && blockIdx.y <= (IMG/TH - 2))
        run(std::integral_constant<bool, false>{});
    else
        run(std::integral_constant<bool, true>{});

    const float C1 = 0.01f * 0.01f;
    const float C2 = 0.03f * 0.03f;
    float local = 0.f;
    #pragma unroll
    for (int o = 0; o < TH; ++o) {
        #pragma unroll
        for (int h = 0; h < 2; ++h) {
            float mux = (float)acc[0][o][h];
            float muy = (float)acc[1][o][h];
            float exx = (float)acc[2][o][h];
            float eyy = (float)acc[3][o][h];
            float exy = (float)acc[4][o][h];
            float mux2 = mux * mux, muy2 = muy * muy, muxy = mux * muy;
            float num = (2.f * muxy + C1) * (2.f * (exy - muxy) + C2);
            float den = (mux2 + muy2 + C1) * ((exx - mux2) + (eyy - muy2) + C2);
            local += num * __builtin_amdgcn_rcpf(den + 1e-8f);
        }
    }

    #pragma unroll
    for (int off = 32; off > 0; off >>= 1)
        local += __shfl_down(local, off, 64);
    if ((cp & 63) == 0) atomicAdd(out_acc, local);
}

// ---------------- Fallback (R4 kernel): used only if ws is too small --------
__global__ void __launch_bounds__(256) fb_tile_kernel(
        const float* __restrict__ xin, const float* __restrict__ yin,
        float* __restrict__ out_acc, GaussW W) {
    __shared__ __align__(16) f16 hb[5][RH * SH2];
    __shared__ float wsum[4];
    const int tid = threadIdx.x;
    const int bx = blockIdx.x, by = blockIdx.y;
    const size_t ibase = (size_t)blockIdx.z * (IMG * IMG);
    const float* __restrict__ xb = xin + ibase;
    const float* __restrict__ yb = yin + ibase;

    if (tid < RH * (TW / 8)) {
        const int r  = tid >> 3;
        const int cg = tid & 7;
        const int gy  = by * TH - HALO + r;
        const int gx0 = bx * TW - HALO + cg * 8;
        float xv[18], yv[18];
        const float* xr = xb + (size_t)gy * IMG;
        const float* yr = yb + (size_t)gy * IMG;
        const bool interior = (bx >= 1 && bx <= 6 && by >= 1 && by <= 30);
        if (interior) {
            xv[0] = xr[gx0];  yv[0] = yr[gx0];
            #pragma unroll
            for (int q = 0; q < 4; ++q) {
                float4 a = *(const float4*)(xr + gx0 + 1 + 4*q);
                float4 b = *(const float4*)(yr + gx0 + 1 + 4*q);
                xv[1+4*q] = a.x; xv[2+4*q] = a.y; xv[3+4*q] = a.z; xv[4+4*q] = a.w;
                yv[1+4*q] = b.x; yv[2+4*q] = b.y; yv[3+4*q] = b.z; yv[4+4*q] = b.w;
            }
            xv[17] = xr[gx0 + 17];  yv[17] = yr[gx0 + 17];
        } else {
            const bool rowok = ((unsigned)gy < IMG);
            #pragma unroll
            for (int j = 0; j < 18; ++j) {
                int gx = gx0 + j;
                bool ok = rowok && ((unsigned)gx < IMG);
                xv[j] = ok ? xr[gx] : 0.f;
                yv[j] = ok ? yr[gx] : 0.f;
            }
        }
        float ax[8]={0,0,0,0,0,0,0,0}, ay[8]={0,0,0,0,0,0,0,0};
        float axx[8]={0,0,0,0,0,0,0,0}, ayy[8]={0,0,0,0,0,0,0,0}, axy[8]={0,0,0,0,0,0,0,0};
        #pragma unroll
        for (int j = 0; j < 18; ++j) {
            float xs = xv[j], ys = yv[j];
            float xx = xs*xs, yy = ys*ys, xy = xs*ys;
            #pragma unroll
            for (int o = 0; o < 8; ++o) {
                int k = j - o;
                if (k >= 0 && k < WIN) {
                    float wk = W.w[k];
                    ax[o]+=wk*xs; ay[o]+=wk*ys; axx[o]+=wk*xx; ayy[o]+=wk*yy; axy[o]+=wk*xy;
                }
            }
        }
        const int ob = r * SH2 + cg * 8;
        uint4 u;
        u.x=pk2(ax[0],ax[1]); u.y=pk2(ax[2],ax[3]); u.z=pk2(ax[4],ax[5]); u.w=pk2(ax[6],ax[7]);
        *(uint4*)&hb[0][ob] = u;
        u.x=pk2(ay[0],ay[1]); u.y=pk2(ay[2],ay[3]); u.z=pk2(ay[4],ay[5]); u.w=pk2(ay[6],ay[7]);
        *(uint4*)&hb[1][ob] = u;
        u.x=pk2(axx[0],axx[1]); u.y=pk2(axx[2],axx[3]); u.z=pk2(axx[4],axx[5]); u.w=pk2(axx[6],axx[7]);
        *(uint4*)&hb[2][ob] = u;
        u.x=pk2(ayy[0],ayy[1]); u.y=pk2(ayy[2],ayy[3]); u.z=pk2(ayy[4],ayy[5]); u.w=pk2(ayy[6],ayy[7]);
        *(uint4*)&hb[3][ob] = u;
        u.x=pk2(axy[0],axy[1]); u.y=pk2(axy[2],axy[3]); u.z=pk2(axy[4],axy[5]); u.w=pk2(axy[6],axy[7]);
        *(uint4*)&hb[4][ob] = u;
    }
    __syncthreads();

    const int c2 = tid & 31;
    const int r0 = (tid >> 5) << 1;
    const int hbase = 2 * c2;
    h2 w2[WIN];
    #pragma unroll
    for (int k = 0; k < WIN; ++k) { f16 wk = (f16)W.w[k]; w2[k] = (h2){wk, wk}; }
    h2 acc[5][2];
    #pragma unroll
    for (int f = 0; f < 5; ++f) { acc[f][0]=(h2){(f16)0,(f16)0}; acc[f][1]=(h2){(f16)0,(f16)0}; }
    #pragma unroll
    for (int f = 0; f < 5; ++f) {
        const f16* buf = hb[f];
        h2 v[12];
        #pragma unroll
        for (int k = 0; k < 12; ++k) v[k] = *(const h2*)&buf[(r0 + k) * SH2 + hbase];
        #pragma unroll
        for (int k = 0; k < WIN; ++k) { acc[f][0] += w2[k]*v[k]; acc[f][1] += w2[k]*v[k+1]; }
    }
    const float C1 = 0.01f * 0.01f;
    const float C2 = 0.03f * 0.03f;
    float local = 0.f;
    #pragma unroll
    for (int o = 0; o < 2; ++o)
        #pragma unroll
        for (int h = 0; h < 2; ++h) {
            float mux=(float)acc[0][o][h], muy=(float)acc[1][o][h];
            float exx=(float)acc[2][o][h], eyy=(float)acc[3][o][h], exy=(float)acc[4][o][h];
            float mux2=mux*mux, muy2=muy*muy, muxy=mux*muy;
            float num=(2.f*muxy+C1)*(2.f*(exy-muxy)+C2);
            float den=(mux2+muy2+C1)*((exx-mux2)+(eyy-muy2)+C2);
            local += num * __builtin_amdgcn_rcpf(den + 1e-8f);
        }
    #pragma unroll
    for (int off = 32; off > 0; off >>= 1) local += __shfl_down(local, off, 64);
    if ((tid & 63) == 0) wsum[tid >> 6] = local;
    __syncthreads();
    if (tid == 0) atomicAdd(out_acc, wsum[0]+wsum[1]+wsum[2]+wsum[3]);
}

extern "C" void kernel_launch(void* const* d_in, const int* in_sizes, int n_in,
                              void* d_out, int out_size, void* d_ws, size_t ws_size,
                              hipStream_t stream) {
    const float* x = (const float*)d_in[0];
    const float* y = (const float*)d_in[1];
    float* out = (float*)d_out;

    GaussW gw;
    double g[WIN], s = 0.0;
    for (int i = 0; i < WIN; ++i) {
        double d = (double)(i - WIN / 2);
        g[i] = exp(-(d * d) / (2.0 * 1.5 * 1.5));
        s += g[i];
    }
    for (int i = 0; i < WIN; ++i) gw.w[i] = (float)(g[i] / s);

    hipLaunchKernelGGL(zero_kernel, dim3(1), dim3(64), 0, stream, out);

    // per image: A = 512*256*16 B = 2 MB, B = 512*256*4 B = 0.5 MB
    auto need = [](int n) { return (size_t)n * IMG * CPR * 20; };
    int chunk = NIMG;                       // 48 -> 24 -> 12 -> 6 -> 3
    while (chunk > 3 && need(chunk) > ws_size) chunk >>= 1;

    if (need(chunk) <= ws_size) {
        uint4*    wsA = (uint4*)d_ws;
        unsigned* wsB = (unsigned*)((char*)d_ws + (size_t)chunk * IMG * CPR * 16);
        for (int off = 0; off < NIMG; off += chunk) {
            hipLaunchKernelGGL(k1_hblur, dim3(1, IMG/4, chunk), dim3(256), 0, stream,
                               x, y, wsA, wsB, off, gw);
            hipLaunchKernelGGL(k2_vblur, dim3(1, IMG/TH, chunk), dim3(256), 0, stream,
                               wsA, wsB, out, gw);
        }
    } else {
        hipLaunchKernelGGL(fb_tile_kernel, dim3(IMG/TW, IMG/TH, NIMG), dim3(256),
                           0, stream, x, y, out, gw);
    }

    hipLaunchKernelGGL(finish_kernel, dim3(1), dim3(64), 0, stream, out);
}

// Round 8
// 233.875 us; speedup vs baseline: 1.0652x; 1.0652x over previous
//
#include <hip/hip_runtime.h>
#include <cmath>
#include <utility>

#define WIN 11
#define HALO 5
#define IMG 512
#define TW 64
#define TH 16
#define RH (TH + 2*HALO)
#define SH2 72
#define NIMG 48
#define NPIX (16.0 * 3.0 * 512.0 * 512.0)
#define CPR (IMG/2)          /* 256 col-pairs (uint4s) per row */

typedef _Float16 f16;
typedef _Float16 h2 __attribute__((ext_vector_type(2)));

struct GaussW { float w[WIN]; };

__device__ __forceinline__ unsigned pk2(float a, float b) {
    auto h = __builtin_amdgcn_cvt_pkrtz(a, b);   // __fp16 ext_vector(2)
    return __builtin_bit_cast(unsigned, h);
}
__device__ __forceinline__ h2 uph(unsigned u) {
    return __builtin_bit_cast(h2, u);
}

__global__ void __launch_bounds__(64) zero_kernel(float* out) {
    if (threadIdx.x == 0) out[0] = 0.f;
}

__global__ void __launch_bounds__(64) finish_kernel(float* out) {
    if (threadIdx.x == 0)
        out[0] = 1.0f - out[0] * (float)(1.0 / NPIX);
}

// ---------------- K1: horizontal blur of 4 fields -> interleaved ws ---------
// ws[(lz*IMG + row)*CPR + cp] = uint4{ pk(x), pk(y), pk(x^2+y^2), pk(xy) }
// 4 output cols per thread, 128 threads per row, 2 rows per block.
__global__ void __launch_bounds__(256) k1_hblur(
        const float* __restrict__ xin, const float* __restrict__ yin,
        uint4* __restrict__ ws, int imgOff, GaussW W) {
    const int tid = threadIdx.x;
    const int c   = tid & 127;                   // out cols 4c..4c+3
    const int row = blockIdx.y * 2 + (tid >> 7);
    const int lz  = blockIdx.z;
    const size_t rbase = ((size_t)(imgOff + lz) * IMG + row) * IMG;
    const float* xr = xin + rbase;
    const float* yr = yin + rbase;
    const int gx0 = c * 4 - 5;                   // window cols gx0..gx0+13

    float xv[14], yv[14];
    if (c >= 2 && c <= 125) {
        // 4c-4 is 4-aligned: three aligned float4 runs cover [4c-4, 4c+7]
        xv[0] = xr[gx0];  yv[0] = yr[gx0];
        #pragma unroll
        for (int q = 0; q < 3; ++q) {
            float4 a = *(const float4*)(xr + gx0 + 1 + 4*q);
            float4 b = *(const float4*)(yr + gx0 + 1 + 4*q);
            xv[1+4*q] = a.x; xv[2+4*q] = a.y; xv[3+4*q] = a.z; xv[4+4*q] = a.w;
            yv[1+4*q] = b.x; yv[2+4*q] = b.y; yv[3+4*q] = b.z; yv[4+4*q] = b.w;
        }
        xv[13] = xr[gx0 + 13];  yv[13] = yr[gx0 + 13];
    } else {
        #pragma unroll
        for (int j = 0; j < 14; ++j) {
            int gx = gx0 + j;
            bool ok = ((unsigned)gx < IMG);
            xv[j] = ok ? xr[gx] : 0.f;
            yv[j] = ok ? yr[gx] : 0.f;
        }
    }

    float ax[4]  = {0,0,0,0}, ay[4] = {0,0,0,0};
    float as[4]  = {0,0,0,0}, axy[4] = {0,0,0,0};
    #pragma unroll
    for (int j = 0; j < 14; ++j) {
        float xs = xv[j], ys = yv[j];
        float xy = xs * ys;
        float ss = fmaf(xs, xs, ys * ys);        // x^2 + y^2 in one field
        #pragma unroll
        for (int o = 0; o < 4; ++o) {
            int k = j - o;
            if (k >= 0 && k < WIN) {
                float wk = W.w[k];
                ax[o]  += wk * xs;
                ay[o]  += wk * ys;
                as[o]  += wk * ss;
                axy[o] += wk * xy;
            }
        }
    }

    const size_t ob = ((size_t)lz * IMG + row) * CPR + 2 * c;
    uint4 u0, u1;
    u0.x = pk2(ax[0],  ax[1]);  u0.y = pk2(ay[0],  ay[1]);
    u0.z = pk2(as[0],  as[1]);  u0.w = pk2(axy[0], axy[1]);
    u1.x = pk2(ax[2],  ax[3]);  u1.y = pk2(ay[2],  ay[3]);
    u1.z = pk2(as[2],  as[3]);  u1.w = pk2(axy[2], axy[3]);
    ws[ob]     = u0;
    ws[ob + 1] = u1;
}

// ---------------- K2: vertical blur + SSIM + reduce -------------------------
// Thread owns one col-pair over a 16-row strip; ONE uint4 load per row-step,
// depth-4 register ring prefetch. No LDS, no barrier.
__global__ void __launch_bounds__(256) k2_vblur(
        const uint4* __restrict__ ws, float* __restrict__ out_acc, GaussW W) {
    const int cp = threadIdx.x;                  // col-pair 0..255
    const int r0 = blockIdx.y * TH;
    const int lz = blockIdx.z;
    const size_t base = (size_t)lz * IMG * CPR + cp;

    h2 w2[WIN];
    #pragma unroll
    for (int k = 0; k < WIN; ++k) {
        f16 wk = (f16)W.w[k];
        w2[k] = (h2){wk, wk};
    }

    h2 acc[4][TH];
    #pragma unroll
    for (int f = 0; f < 4; ++f)
        #pragma unroll
        for (int o = 0; o < TH; ++o) acc[f][o] = (h2){(f16)0, (f16)0};

    auto run = [&](auto guard_c) {
        constexpr bool G = decltype(guard_c)::value;
        uint4 buf[4];
        auto ld = [&](int j) {
            int r = r0 - HALO + j;
            uint4 v;
            if (G && ((unsigned)r >= IMG)) v = make_uint4(0u, 0u, 0u, 0u);
            else                           v = ws[base + (size_t)r * CPR];
            buf[j & 3] = v;
        };
        ld(0); ld(1); ld(2); ld(3);
        #pragma unroll
        for (int j = 0; j < TH + 2*HALO; ++j) {
            uint4 cur = buf[j & 3];
            if (j + 4 < TH + 2*HALO) ld(j + 4);
            h2 v0 = uph(cur.x), v1 = uph(cur.y), v2 = uph(cur.z), v3 = uph(cur.w);
            #pragma unroll
            for (int o = 0; o < TH; ++o) {
                int k = j - o;
                if (k >= 0 && k < WIN) {
                    acc[0][o] += w2[k] * v0;
                    acc[1][o] += w2[k] * v1;
                    acc[2][o] += w2[k] * v2;
                    acc[3][o] += w2[k] * v3;
                }
            }
        }
    };
    if (blockIdx.y >= 1 && blockIdx.y <= (IMG/TH - 2))
        run(std::integral_constant<bool, false>{});
    else
        run(std::integral_constant<bool, true>{});

    const float C1 = 0.01f * 0.01f;
    const float C2 = 0.03f * 0.03f;
    float local = 0.f;
    #pragma unroll
    for (int o = 0; o < TH; ++o) {
        #pragma unroll
        for (int h = 0; h < 2; ++h) {
            float mux = (float)acc[0][o][h];
            float muy = (float)acc[1][o][h];
            float es  = (float)acc[2][o][h];     // E[x^2 + y^2]
            float exy = (float)acc[3][o][h];
            float mux2 = mux * mux, muy2 = muy * muy, muxy = mux * muy;
            float num = (2.f * muxy + C1) * (2.f * (exy - muxy) + C2);
            float den = (mux2 + muy2 + C1) * ((es - mux2 - muy2) + C2);
            local += num * __builtin_amdgcn_rcpf(den + 1e-8f);
        }
    }

    #pragma unroll
    for (int off = 32; off > 0; off >>= 1)
        local += __shfl_down(local, off, 64);
    if ((cp & 63) == 0) atomicAdd(out_acc, local);
}

// ---------------- Fallback (R4 kernel): used only if ws is too small --------
__global__ void __launch_bounds__(256) fb_tile_kernel(
        const float* __restrict__ xin, const float* __restrict__ yin,
        float* __restrict__ out_acc, GaussW W) {
    __shared__ __align__(16) f16 hb[5][RH * SH2];
    __shared__ float wsum[4];
    const int tid = threadIdx.x;
    const int bx = blockIdx.x, by = blockIdx.y;
    const size_t ibase = (size_t)blockIdx.z * (IMG * IMG);
    const float* __restrict__ xb = xin + ibase;
    const float* __restrict__ yb = yin + ibase;

    if (tid < RH * (TW / 8)) {
        const int r  = tid >> 3;
        const int cg = tid & 7;
        const int gy  = by * TH - HALO + r;
        const int gx0 = bx * TW - HALO + cg * 8;
        float xv[18], yv[18];
        const float* xr = xb + (size_t)gy * IMG;
        const float* yr = yb + (size_t)gy * IMG;
        const bool interior = (bx >= 1 && bx <= 6 && by >= 1 && by <= 30);
        if (interior) {
            xv[0] = xr[gx0];  yv[0] = yr[gx0];
            #pragma unroll
            for (int q = 0; q < 4; ++q) {
                float4 a = *(const float4*)(xr + gx0 + 1 + 4*q);
                float4 b = *(const float4*)(yr + gx0 + 1 + 4*q);
                xv[1+4*q] = a.x; xv[2+4*q] = a.y; xv[3+4*q] = a.z; xv[4+4*q] = a.w;
                yv[1+4*q] = b.x; yv[2+4*q] = b.y; yv[3+4*q] = b.z; yv[4+4*q] = b.w;
            }
            xv[17] = xr[gx0 + 17];  yv[17] = yr[gx0 + 17];
        } else {
            const bool rowok = ((unsigned)gy < IMG);
            #pragma unroll
            for (int j = 0; j < 18; ++j) {
                int gx = gx0 + j;
                bool ok = rowok && ((unsigned)gx < IMG);
                xv[j] = ok ? xr[gx] : 0.f;
                yv[j] = ok ? yr[gx] : 0.f;
            }
        }
        float ax[8]={0,0,0,0,0,0,0,0}, ay[8]={0,0,0,0,0,0,0,0};
        float axx[8]={0,0,0,0,0,0,0,0}, ayy[8]={0,0,0,0,0,0,0,0}, axy[8]={0,0,0,0,0,0,0,0};
        #pragma unroll
        for (int j = 0; j < 18; ++j) {
            float xs = xv[j], ys = yv[j];
            float xx = xs*xs, yy = ys*ys, xy = xs*ys;
            #pragma unroll
            for (int o = 0; o < 8; ++o) {
                int k = j - o;
                if (k >= 0 && k < WIN) {
                    float wk = W.w[k];
                    ax[o]+=wk*xs; ay[o]+=wk*ys; axx[o]+=wk*xx; ayy[o]+=wk*yy; axy[o]+=wk*xy;
                }
            }
        }
        const int ob = r * SH2 + cg * 8;
        uint4 u;
        u.x=pk2(ax[0],ax[1]); u.y=pk2(ax[2],ax[3]); u.z=pk2(ax[4],ax[5]); u.w=pk2(ax[6],ax[7]);
        *(uint4*)&hb[0][ob] = u;
        u.x=pk2(ay[0],ay[1]); u.y=pk2(ay[2],ay[3]); u.z=pk2(ay[4],ay[5]); u.w=pk2(ay[6],ay[7]);
        *(uint4*)&hb[1][ob] = u;
        u.x=pk2(axx[0],axx[1]); u.y=pk2(axx[2],axx[3]); u.z=pk2(axx[4],axx[5]); u.w=pk2(axx[6],axx[7]);
        *(uint4*)&hb[2][ob] = u;
        u.x=pk2(ayy[0],ayy[1]); u.y=pk2(ayy[2],ayy[3]); u.z=pk2(ayy[4],ayy[5]); u.w=pk2(ayy[6],ayy[7]);
        *(uint4*)&hb[3][ob] = u;
        u.x=pk2(axy[0],axy[1]); u.y=pk2(axy[2],axy[3]); u.z=pk2(axy[4],axy[5]); u.w=pk2(axy[6],axy[7]);
        *(uint4*)&hb[4][ob] = u;
    }
    __syncthreads();

    const int c2 = tid & 31;
    const int r0 = (tid >> 5) << 1;
    const int hbase = 2 * c2;
    h2 w2[WIN];
    #pragma unroll
    for (int k = 0; k < WIN; ++k) { f16 wk = (f16)W.w[k]; w2[k] = (h2){wk, wk}; }
    h2 acc[5][2];
    #pragma unroll
    for (int f = 0; f < 5; ++f) { acc[f][0]=(h2){(f16)0,(f16)0}; acc[f][1]=(h2){(f16)0,(f16)0}; }
    #pragma unroll
    for (int f = 0; f < 5; ++f) {
        const f16* buf = hb[f];
        h2 v[12];
        #pragma unroll
        for (int k = 0; k < 12; ++k) v[k] = *(const h2*)&buf[(r0 + k) * SH2 + hbase];
        #pragma unroll
        for (int k = 0; k < WIN; ++k) { acc[f][0] += w2[k]*v[k]; acc[f][1] += w2[k]*v[k+1]; }
    }
    const float C1 = 0.01f * 0.01f;
    const float C2 = 0.03f * 0.03f;
    float local = 0.f;
    #pragma unroll
    for (int o = 0; o < 2; ++o)
        #pragma unroll
        for (int h = 0; h < 2; ++h) {
            float mux=(float)acc[0][o][h], muy=(float)acc[1][o][h];
            float exx=(float)acc[2][o][h], eyy=(float)acc[3][o][h], exy=(float)acc[4][o][h];
            float mux2=mux*mux, muy2=muy*muy, muxy=mux*muy;
            float num=(2.f*muxy+C1)*(2.f*(exy-muxy)+C2);
            float den=(mux2+muy2+C1)*((exx-mux2)+(eyy-muy2)+C2);
            local += num * __builtin_amdgcn_rcpf(den + 1e-8f);
        }
    #pragma unroll
    for (int off = 32; off > 0; off >>= 1) local += __shfl_down(local, off, 64);
    if ((tid & 63) == 0) wsum[tid >> 6] = local;
    __syncthreads();
    if (tid == 0) atomicAdd(out_acc, wsum[0]+wsum[1]+wsum[2]+wsum[3]);
}

extern "C" void kernel_launch(void* const* d_in, const int* in_sizes, int n_in,
                              void* d_out, int out_size, void* d_ws, size_t ws_size,
                              hipStream_t stream) {
    const float* x = (const float*)d_in[0];
    const float* y = (const float*)d_in[1];
    float* out = (float*)d_out;

    GaussW gw;
    double g[WIN], s = 0.0;
    for (int i = 0; i < WIN; ++i) {
        double d = (double)(i - WIN / 2);
        g[i] = exp(-(d * d) / (2.0 * 1.5 * 1.5));
        s += g[i];
    }
    for (int i = 0; i < WIN; ++i) gw.w[i] = (float)(g[i] / s);

    hipLaunchKernelGGL(zero_kernel, dim3(1), dim3(64), 0, stream, out);

    // per image: 512 rows * 256 col-pairs * 16 B = 2 MB
    auto need = [](int n) { return (size_t)n * IMG * CPR * sizeof(uint4); };
    int chunk = NIMG;                       // 48 -> 24 -> 12 -> 6 -> 3
    while (chunk > 3 && need(chunk) > ws_size) chunk >>= 1;

    if (need(chunk) <= ws_size) {
        uint4* ws = (uint4*)d_ws;
        for (int off = 0; off < NIMG; off += chunk) {
            hipLaunchKernelGGL(k1_hblur, dim3(1, IMG/2, chunk), dim3(256), 0, stream,
                               x, y, ws, off, gw);
            hipLaunchKernelGGL(k2_vblur, dim3(1, IMG/TH, chunk), dim3(256), 0, stream,
                               ws, out, gw);
        }
    } else {
        hipLaunchKernelGGL(fb_tile_kernel, dim3(IMG/TW, IMG/TH, NIMG), dim3(256),
                           0, stream, x, y, out, gw);
    }

    hipLaunchKernelGGL(finish_kernel, dim3(1), dim3(64), 0, stream, out);
}

// Round 9
// 232.211 us; speedup vs baseline: 1.0728x; 1.0072x over previous
//
#include <hip/hip_runtime.h>
#include <cmath>

#define WIN 11
#define HALO 5
#define IMG 512
#define TW 64
#define TH 16
#define RH (TH + 2*HALO)
#define SH2 72
#define NIMG 48
#define NPIX (16.0 * 3.0 * 512.0 * 512.0)
#define CPR (IMG/2)          /* 256 col-pairs (uint4s) per row */

typedef _Float16 f16;
typedef _Float16 h2 __attribute__((ext_vector_type(2)));

struct GaussW { float w[WIN]; };

__device__ __forceinline__ unsigned pk2(float a, float b) {
    auto h = __builtin_amdgcn_cvt_pkrtz(a, b);   // __fp16 ext_vector(2)
    return __builtin_bit_cast(unsigned, h);
}
__device__ __forceinline__ h2 uph(unsigned u) {
    return __builtin_bit_cast(h2, u);
}

__global__ void __launch_bounds__(64) zero_kernel(float* out) {
    if (threadIdx.x == 0) out[0] = 0.f;
}

__global__ void __launch_bounds__(64) finish_kernel(float* out) {
    if (threadIdx.x == 0)
        out[0] = 1.0f - out[0] * (float)(1.0 / NPIX);
}

// ---------------- K1: horizontal blur of 4 fields -> interleaved ws ---------
// ws[(lz*IMG + row)*CPR + cp] = uint4{ pk(x), pk(y), pk(x^2+y^2), pk(xy) }
// 4 output cols per thread, 128 threads per row, 2 rows per block. (R7, kept)
__global__ void __launch_bounds__(256) k1_hblur(
        const float* __restrict__ xin, const float* __restrict__ yin,
        uint4* __restrict__ ws, int imgOff, GaussW W) {
    const int tid = threadIdx.x;
    const int c   = tid & 127;                   // out cols 4c..4c+3
    const int row = blockIdx.y * 2 + (tid >> 7);
    const int lz  = blockIdx.z;
    const size_t rbase = ((size_t)(imgOff + lz) * IMG + row) * IMG;
    const float* xr = xin + rbase;
    const float* yr = yin + rbase;
    const int gx0 = c * 4 - 5;                   // window cols gx0..gx0+13

    float xv[14], yv[14];
    if (c >= 2 && c <= 125) {
        xv[0] = xr[gx0];  yv[0] = yr[gx0];
        #pragma unroll
        for (int q = 0; q < 3; ++q) {
            float4 a = *(const float4*)(xr + gx0 + 1 + 4*q);
            float4 b = *(const float4*)(yr + gx0 + 1 + 4*q);
            xv[1+4*q] = a.x; xv[2+4*q] = a.y; xv[3+4*q] = a.z; xv[4+4*q] = a.w;
            yv[1+4*q] = b.x; yv[2+4*q] = b.y; yv[3+4*q] = b.z; yv[4+4*q] = b.w;
        }
        xv[13] = xr[gx0 + 13];  yv[13] = yr[gx0 + 13];
    } else {
        #pragma unroll
        for (int j = 0; j < 14; ++j) {
            int gx = gx0 + j;
            bool ok = ((unsigned)gx < IMG);
            xv[j] = ok ? xr[gx] : 0.f;
            yv[j] = ok ? yr[gx] : 0.f;
        }
    }

    float ax[4]  = {0,0,0,0}, ay[4] = {0,0,0,0};
    float as[4]  = {0,0,0,0}, axy[4] = {0,0,0,0};
    #pragma unroll
    for (int j = 0; j < 14; ++j) {
        float xs = xv[j], ys = yv[j];
        float xy = xs * ys;
        float ss = fmaf(xs, xs, ys * ys);        // x^2 + y^2 in one field
        #pragma unroll
        for (int o = 0; o < 4; ++o) {
            int k = j - o;
            if (k >= 0 && k < WIN) {
                float wk = W.w[k];
                ax[o]  += wk * xs;
                ay[o]  += wk * ys;
                as[o]  += wk * ss;
                axy[o] += wk * xy;
            }
        }
    }

    const size_t ob = ((size_t)lz * IMG + row) * CPR + 2 * c;
    uint4 u0, u1;
    u0.x = pk2(ax[0],  ax[1]);  u0.y = pk2(ay[0],  ay[1]);
    u0.z = pk2(as[0],  as[1]);  u0.w = pk2(axy[0], axy[1]);
    u1.x = pk2(ax[2],  ax[3]);  u1.y = pk2(ay[2],  ay[3]);
    u1.z = pk2(as[2],  as[3]);  u1.w = pk2(axy[2], axy[3]);
    ws[ob]     = u0;
    ws[ob + 1] = u1;
}

// ---------------- K2: vertical blur + SSIM + reduce (small-code version) ----
// Thread = one col-pair x 4 output rows: 14 uint4 loads -> 176 pk_fma -> SSIM.
// Body ~3 KB: fits L1I (R7's unrolled 26-step body streamed from L2 = the
// 94 us wall; duration was invariant to data location -> I-fetch bound).
// Grid (48,128): z fastest so row-adjacent blocks (+48 dispatch slots,
// 48%8==0) land on the same XCD for L2 reuse of shared halo rows.
__global__ void __launch_bounds__(256) k2_vblur(
        const uint4* __restrict__ ws, float* __restrict__ out_acc, GaussW W) {
    const int cp = threadIdx.x;                  // col-pair 0..255
    const int lz = blockIdx.x;                   // image
    const int by = blockIdx.y;                   // row-group (4 rows)
    const int r0 = by * 4 - HALO;                // first of 14 input rows
    const size_t base = (size_t)lz * IMG * CPR + cp;
    __shared__ float wsum[4];

    h2 w2[WIN];
    #pragma unroll
    for (int k = 0; k < WIN; ++k) {
        f16 wk = (f16)W.w[k];
        w2[k] = (h2){wk, wk};
    }

    uint4 v[14];
    if (by >= 2 && by <= 125) {
        #pragma unroll
        for (int j = 0; j < 14; ++j)
            v[j] = ws[base + (size_t)(r0 + j) * CPR];
    } else {
        #pragma unroll
        for (int j = 0; j < 14; ++j) {
            int r = r0 + j;
            v[j] = ((unsigned)r < IMG) ? ws[base + (size_t)r * CPR]
                                       : make_uint4(0u, 0u, 0u, 0u);
        }
    }

    const float C1 = 0.01f * 0.01f;
    const float C2 = 0.03f * 0.03f;
    float local = 0.f;
    #pragma unroll
    for (int o = 0; o < 4; ++o) {
        h2 a0 = (h2){(f16)0,(f16)0}, a1 = a0, a2 = a0, a3 = a0;
        #pragma unroll
        for (int k = 0; k < WIN; ++k) {
            uint4 u = v[o + k];
            h2 wk = w2[k];
            a0 += wk * uph(u.x);
            a1 += wk * uph(u.y);
            a2 += wk * uph(u.z);
            a3 += wk * uph(u.w);
        }
        #pragma unroll
        for (int h = 0; h < 2; ++h) {
            float mux = (float)a0[h];
            float muy = (float)a1[h];
            float es  = (float)a2[h];            // E[x^2 + y^2]
            float exy = (float)a3[h];
            float mux2 = mux * mux, muy2 = muy * muy, muxy = mux * muy;
            float num = (2.f * muxy + C1) * (2.f * (exy - muxy) + C2);
            float den = (mux2 + muy2 + C1) * ((es - mux2 - muy2) + C2);
            local += num * __builtin_amdgcn_rcpf(den + 1e-8f);
        }
    }

    #pragma unroll
    for (int off = 32; off > 0; off >>= 1)
        local += __shfl_down(local, off, 64);
    if ((cp & 63) == 0) wsum[cp >> 6] = local;
    __syncthreads();
    if (cp == 0)
        atomicAdd(out_acc, wsum[0] + wsum[1] + wsum[2] + wsum[3]);
}

// ---------------- Fallback (R4 kernel): used only if ws is too small --------
__global__ void __launch_bounds__(256) fb_tile_kernel(
        const float* __restrict__ xin, const float* __restrict__ yin,
        float* __restrict__ out_acc, GaussW W) {
    __shared__ __align__(16) f16 hb[5][RH * SH2];
    __shared__ float wsum[4];
    const int tid = threadIdx.x;
    const int bx = blockIdx.x, by = blockIdx.y;
    const size_t ibase = (size_t)blockIdx.z * (IMG * IMG);
    const float* __restrict__ xb = xin + ibase;
    const float* __restrict__ yb = yin + ibase;

    if (tid < RH * (TW / 8)) {
        const int r  = tid >> 3;
        const int cg = tid & 7;
        const int gy  = by * TH - HALO + r;
        const int gx0 = bx * TW - HALO + cg * 8;
        float xv[18], yv[18];
        const float* xr = xb + (size_t)gy * IMG;
        const float* yr = yb + (size_t)gy * IMG;
        const bool interior = (bx >= 1 && bx <= 6 && by >= 1 && by <= 30);
        if (interior) {
            xv[0] = xr[gx0];  yv[0] = yr[gx0];
            #pragma unroll
            for (int q = 0; q < 4; ++q) {
                float4 a = *(const float4*)(xr + gx0 + 1 + 4*q);
                float4 b = *(const float4*)(yr + gx0 + 1 + 4*q);
                xv[1+4*q] = a.x; xv[2+4*q] = a.y; xv[3+4*q] = a.z; xv[4+4*q] = a.w;
                yv[1+4*q] = b.x; yv[2+4*q] = b.y; yv[3+4*q] = b.z; yv[4+4*q] = b.w;
            }
            xv[17] = xr[gx0 + 17];  yv[17] = yr[gx0 + 17];
        } else {
            const bool rowok = ((unsigned)gy < IMG);
            #pragma unroll
            for (int j = 0; j < 18; ++j) {
                int gx = gx0 + j;
                bool ok = rowok && ((unsigned)gx < IMG);
                xv[j] = ok ? xr[gx] : 0.f;
                yv[j] = ok ? yr[gx] : 0.f;
            }
        }
        float ax[8]={0,0,0,0,0,0,0,0}, ay[8]={0,0,0,0,0,0,0,0};
        float axx[8]={0,0,0,0,0,0,0,0}, ayy[8]={0,0,0,0,0,0,0,0}, axy[8]={0,0,0,0,0,0,0,0};
        #pragma unroll
        for (int j = 0; j < 18; ++j) {
            float xs = xv[j], ys = yv[j];
            float xx = xs*xs, yy = ys*ys, xy = xs*ys;
            #pragma unroll
            for (int o = 0; o < 8; ++o) {
                int k = j - o;
                if (k >= 0 && k < WIN) {
                    float wk = W.w[k];
                    ax[o]+=wk*xs; ay[o]+=wk*ys; axx[o]+=wk*xx; ayy[o]+=wk*yy; axy[o]+=wk*xy;
                }
            }
        }
        const int ob = r * SH2 + cg * 8;
        uint4 u;
        u.x=pk2(ax[0],ax[1]); u.y=pk2(ax[2],ax[3]); u.z=pk2(ax[4],ax[5]); u.w=pk2(ax[6],ax[7]);
        *(uint4*)&hb[0][ob] = u;
        u.x=pk2(ay[0],ay[1]); u.y=pk2(ay[2],ay[3]); u.z=pk2(ay[4],ay[5]); u.w=pk2(ay[6],ay[7]);
        *(uint4*)&hb[1][ob] = u;
        u.x=pk2(axx[0],axx[1]); u.y=pk2(axx[2],axx[3]); u.z=pk2(axx[4],axx[5]); u.w=pk2(axx[6],axx[7]);
        *(uint4*)&hb[2][ob] = u;
        u.x=pk2(ayy[0],ayy[1]); u.y=pk2(ayy[2],ayy[3]); u.z=pk2(ayy[4],ayy[5]); u.w=pk2(ayy[6],ayy[7]);
        *(uint4*)&hb[3][ob] = u;
        u.x=pk2(axy[0],axy[1]); u.y=pk2(axy[2],axy[3]); u.z=pk2(axy[4],axy[5]); u.w=pk2(axy[6],axy[7]);
        *(uint4*)&hb[4][ob] = u;
    }
    __syncthreads();

    const int c2 = tid & 31;
    const int r0 = (tid >> 5) << 1;
    const int hbase = 2 * c2;
    h2 w2[WIN];
    #pragma unroll
    for (int k = 0; k < WIN; ++k) { f16 wk = (f16)W.w[k]; w2[k] = (h2){wk, wk}; }
    h2 acc[5][2];
    #pragma unroll
    for (int f = 0; f < 5; ++f) { acc[f][0]=(h2){(f16)0,(f16)0}; acc[f][1]=(h2){(f16)0,(f16)0}; }
    #pragma unroll
    for (int f = 0; f < 5; ++f) {
        const f16* buf = hb[f];
        h2 v[12];
        #pragma unroll
        for (int k = 0; k < 12; ++k) v[k] = *(const h2*)&buf[(r0 + k) * SH2 + hbase];
        #pragma unroll
        for (int k = 0; k < WIN; ++k) { acc[f][0] += w2[k]*v[k]; acc[f][1] += w2[k]*v[k+1]; }
    }
    const float C1 = 0.01f * 0.01f;
    const float C2 = 0.03f * 0.03f;
    float local = 0.f;
    #pragma unroll
    for (int o = 0; o < 2; ++o)
        #pragma unroll
        for (int h = 0; h < 2; ++h) {
            float mux=(float)acc[0][o][h], muy=(float)acc[1][o][h];
            float exx=(float)acc[2][o][h], eyy=(float)acc[3][o][h], exy=(float)acc[4][o][h];
            float mux2=mux*mux, muy2=muy*muy, muxy=mux*muy;
            float num=(2.f*muxy+C1)*(2.f*(exy-muxy)+C2);
            float den=(mux2+muy2+C1)*((exx-mux2)+(eyy-muy2)+C2);
            local += num * __builtin_amdgcn_rcpf(den + 1e-8f);
        }
    #pragma unroll
    for (int off = 32; off > 0; off >>= 1) local += __shfl_down(local, off, 64);
    if ((tid & 63) == 0) wsum[tid >> 6] = local;
    __syncthreads();
    if (tid == 0) atomicAdd(out_acc, wsum[0]+wsum[1]+wsum[2]+wsum[3]);
}

extern "C" void kernel_launch(void* const* d_in, const int* in_sizes, int n_in,
                              void* d_out, int out_size, void* d_ws, size_t ws_size,
                              hipStream_t stream) {
    const float* x = (const float*)d_in[0];
    const float* y = (const float*)d_in[1];
    float* out = (float*)d_out;

    GaussW gw;
    double g[WIN], s = 0.0;
    for (int i = 0; i < WIN; ++i) {
        double d = (double)(i - WIN / 2);
        g[i] = exp(-(d * d) / (2.0 * 1.5 * 1.5));
        s += g[i];
    }
    for (int i = 0; i < WIN; ++i) gw.w[i] = (float)(g[i] / s);

    hipLaunchKernelGGL(zero_kernel, dim3(1), dim3(64), 0, stream, out);

    // per image: 512 rows * 256 col-pairs * 16 B = 2 MB
    auto need = [](int n) { return (size_t)n * IMG * CPR * sizeof(uint4); };
    int chunk = NIMG;                       // 48 -> 24 -> 12 -> 6 -> 3
    while (chunk > 3 && need(chunk) > ws_size) chunk >>= 1;

    if (need(chunk) <= ws_size) {
        uint4* ws = (uint4*)d_ws;
        for (int off = 0; off < NIMG; off += chunk) {
            hipLaunchKernelGGL(k1_hblur, dim3(1, IMG/2, chunk), dim3(256), 0, stream,
                               x, y, ws, off, gw);
            hipLaunchKernelGGL(k2_vblur, dim3(chunk, IMG/4, 1), dim3(256), 0, stream,
                               ws, out, gw);
        }
    } else {
        hipLaunchKernelGGL(fb_tile_kernel, dim3(IMG/TW, IMG/TH, NIMG), dim3(256),
                           0, stream, x, y, out, gw);
    }

    hipLaunchKernelGGL(finish_kernel, dim3(1), dim3(64), 0, stream, out);
}

// Round 10
// 168.931 us; speedup vs baseline: 1.4747x; 1.3746x over previous
//
#include <hip/hip_runtime.h>
#include <cmath>

#define WIN 11
#define HALO 5
#define IMG 512
#define TW 64
#define TH 16
#define RH (TH + 2*HALO)
#define SH2 72
#define NIMG 48
#define NPIX (16.0 * 3.0 * 512.0 * 512.0)
#define CPR (IMG/2)          /* 256 col-pairs (uint4s) per row */
#define NPART (NIMG * (IMG/4))   /* 6144 per-block partials */

typedef _Float16 f16;
typedef _Float16 h2 __attribute__((ext_vector_type(2)));

struct GaussW { float w[WIN]; };

__device__ __forceinline__ unsigned pk2(float a, float b) {
    auto h = __builtin_amdgcn_cvt_pkrtz(a, b);   // __fp16 ext_vector(2)
    return __builtin_bit_cast(unsigned, h);
}
__device__ __forceinline__ h2 uph(unsigned u) {
    return __builtin_bit_cast(h2, u);
}

__global__ void __launch_bounds__(64) zero_kernel(float* out) {
    if (threadIdx.x == 0) out[0] = 0.f;
}

__global__ void __launch_bounds__(64) finish_kernel(float* out) {
    if (threadIdx.x == 0)
        out[0] = 1.0f - out[0] * (float)(1.0 / NPIX);
}

// ---------------- K1: horizontal blur of 4 fields -> interleaved ws ---------
// ws[(lz*IMG + row)*CPR + cp] = uint4{ pk(x), pk(y), pk(x^2+y^2), pk(xy) }
__global__ void __launch_bounds__(256) k1_hblur(
        const float* __restrict__ xin, const float* __restrict__ yin,
        uint4* __restrict__ ws, int imgOff, GaussW W) {
    const int tid = threadIdx.x;
    const int c   = tid & 127;                   // out cols 4c..4c+3
    const int row = blockIdx.y * 2 + (tid >> 7);
    const int lz  = blockIdx.z;
    const size_t rbase = ((size_t)(imgOff + lz) * IMG + row) * IMG;
    const float* xr = xin + rbase;
    const float* yr = yin + rbase;
    const int gx0 = c * 4 - 5;                   // window cols gx0..gx0+13

    float xv[14], yv[14];
    if (c >= 2 && c <= 125) {
        xv[0] = xr[gx0];  yv[0] = yr[gx0];
        #pragma unroll
        for (int q = 0; q < 3; ++q) {
            float4 a = *(const float4*)(xr + gx0 + 1 + 4*q);
            float4 b = *(const float4*)(yr + gx0 + 1 + 4*q);
            xv[1+4*q] = a.x; xv[2+4*q] = a.y; xv[3+4*q] = a.z; xv[4+4*q] = a.w;
            yv[1+4*q] = b.x; yv[2+4*q] = b.y; yv[3+4*q] = b.z; yv[4+4*q] = b.w;
        }
        xv[13] = xr[gx0 + 13];  yv[13] = yr[gx0 + 13];
    } else {
        #pragma unroll
        for (int j = 0; j < 14; ++j) {
            int gx = gx0 + j;
            bool ok = ((unsigned)gx < IMG);
            xv[j] = ok ? xr[gx] : 0.f;
            yv[j] = ok ? yr[gx] : 0.f;
        }
    }

    float ax[4]  = {0,0,0,0}, ay[4] = {0,0,0,0};
    float as[4]  = {0,0,0,0}, axy[4] = {0,0,0,0};
    #pragma unroll
    for (int j = 0; j < 14; ++j) {
        float xs = xv[j], ys = yv[j];
        float xy = xs * ys;
        float ss = fmaf(xs, xs, ys * ys);        // x^2 + y^2 in one field
        #pragma unroll
        for (int o = 0; o < 4; ++o) {
            int k = j - o;
            if (k >= 0 && k < WIN) {
                float wk = W.w[k];
                ax[o]  += wk * xs;
                ay[o]  += wk * ys;
                as[o]  += wk * ss;
                axy[o] += wk * xy;
            }
        }
    }

    const size_t ob = ((size_t)lz * IMG + row) * CPR + 2 * c;
    uint4 u0, u1;
    u0.x = pk2(ax[0],  ax[1]);  u0.y = pk2(ay[0],  ay[1]);
    u0.z = pk2(as[0],  as[1]);  u0.w = pk2(axy[0], axy[1]);
    u1.x = pk2(ax[2],  ax[3]);  u1.y = pk2(ay[2],  ay[3]);
    u1.z = pk2(as[2],  as[3]);  u1.w = pk2(axy[2], axy[3]);
    ws[ob]     = u0;
    ws[ob + 1] = u1;
}

// ---------------- K2: vertical blur + SSIM + per-block partial (NO atomics) -
// Thread = one col-pair x 4 output rows: 14 uint4 loads -> 176 pk_fma -> SSIM.
// Partial sum stored to partial[(imgOff+lz)*128 + by] with a plain store.
// (R8 post-mortem: one atomicAdd/block to out[0] serialized at ~14 ns each =
//  the 85-200 us plateau across ALL prior rounds.)
__global__ void __launch_bounds__(256) k2_vblur(
        const uint4* __restrict__ ws, float* __restrict__ partial,
        int imgOff, GaussW W) {
    const int cp = threadIdx.x;                  // col-pair 0..255
    const int lz = blockIdx.x;                   // image (within chunk)
    const int by = blockIdx.y;                   // row-group (4 rows)
    const int r0 = by * 4 - HALO;                // first of 14 input rows
    const size_t base = (size_t)lz * IMG * CPR + cp;
    __shared__ float wsum[4];

    h2 w2[WIN];
    #pragma unroll
    for (int k = 0; k < WIN; ++k) {
        f16 wk = (f16)W.w[k];
        w2[k] = (h2){wk, wk};
    }

    uint4 v[14];
    if (by >= 2 && by <= 125) {
        #pragma unroll
        for (int j = 0; j < 14; ++j)
            v[j] = ws[base + (size_t)(r0 + j) * CPR];
    } else {
        #pragma unroll
        for (int j = 0; j < 14; ++j) {
            int r = r0 + j;
            v[j] = ((unsigned)r < IMG) ? ws[base + (size_t)r * CPR]
                                       : make_uint4(0u, 0u, 0u, 0u);
        }
    }

    const float C1 = 0.01f * 0.01f;
    const float C2 = 0.03f * 0.03f;
    float local = 0.f;
    #pragma unroll
    for (int o = 0; o < 4; ++o) {
        h2 a0 = (h2){(f16)0,(f16)0}, a1 = a0, a2 = a0, a3 = a0;
        #pragma unroll
        for (int k = 0; k < WIN; ++k) {
            uint4 u = v[o + k];
            h2 wk = w2[k];
            a0 += wk * uph(u.x);
            a1 += wk * uph(u.y);
            a2 += wk * uph(u.z);
            a3 += wk * uph(u.w);
        }
        #pragma unroll
        for (int h = 0; h < 2; ++h) {
            float mux = (float)a0[h];
            float muy = (float)a1[h];
            float es  = (float)a2[h];            // E[x^2 + y^2]
            float exy = (float)a3[h];
            float mux2 = mux * mux, muy2 = muy * muy, muxy = mux * muy;
            float num = (2.f * muxy + C1) * (2.f * (exy - muxy) + C2);
            float den = (mux2 + muy2 + C1) * ((es - mux2 - muy2) + C2);
            local += num * __builtin_amdgcn_rcpf(den + 1e-8f);
        }
    }

    #pragma unroll
    for (int off = 32; off > 0; off >>= 1)
        local += __shfl_down(local, off, 64);
    if ((cp & 63) == 0) wsum[cp >> 6] = local;
    __syncthreads();
    if (cp == 0)
        partial[(size_t)(imgOff + lz) * (IMG/4) + by] =
            wsum[0] + wsum[1] + wsum[2] + wsum[3];
}

// ---------------- Final reduce: 6144 partials -> out[0], one block ----------
__global__ void __launch_bounds__(256) reduce_kernel(
        const float* __restrict__ partial, float* __restrict__ out) {
    __shared__ float wsum[4];
    const int tid = threadIdx.x;
    float s = 0.f;
    for (int i = tid; i < NPART; i += 256) s += partial[i];
    #pragma unroll
    for (int off = 32; off > 0; off >>= 1)
        s += __shfl_down(s, off, 64);
    if ((tid & 63) == 0) wsum[tid >> 6] = s;
    __syncthreads();
    if (tid == 0)
        out[0] = 1.0f - (wsum[0] + wsum[1] + wsum[2] + wsum[3]) * (float)(1.0 / NPIX);
}

// ---------------- Fallback (R4 kernel): used only if ws is too small --------
__global__ void __launch_bounds__(256) fb_tile_kernel(
        const float* __restrict__ xin, const float* __restrict__ yin,
        float* __restrict__ out_acc, GaussW W) {
    __shared__ __align__(16) f16 hb[5][RH * SH2];
    __shared__ float wsum[4];
    const int tid = threadIdx.x;
    const int bx = blockIdx.x, by = blockIdx.y;
    const size_t ibase = (size_t)blockIdx.z * (IMG * IMG);
    const float* __restrict__ xb = xin + ibase;
    const float* __restrict__ yb = yin + ibase;

    if (tid < RH * (TW / 8)) {
        const int r  = tid >> 3;
        const int cg = tid & 7;
        const int gy  = by * TH - HALO + r;
        const int gx0 = bx * TW - HALO + cg * 8;
        float xv[18], yv[18];
        const float* xr = xb + (size_t)gy * IMG;
        const float* yr = yb + (size_t)gy * IMG;
        const bool interior = (bx >= 1 && bx <= 6 && by >= 1 && by <= 30);
        if (interior) {
            xv[0] = xr[gx0];  yv[0] = yr[gx0];
            #pragma unroll
            for (int q = 0; q < 4; ++q) {
                float4 a = *(const float4*)(xr + gx0 + 1 + 4*q);
                float4 b = *(const float4*)(yr + gx0 + 1 + 4*q);
                xv[1+4*q] = a.x; xv[2+4*q] = a.y; xv[3+4*q] = a.z; xv[4+4*q] = a.w;
                yv[1+4*q] = b.x; yv[2+4*q] = b.y; yv[3+4*q] = b.z; yv[4+4*q] = b.w;
            }
            xv[17] = xr[gx0 + 17];  yv[17] = yr[gx0 + 17];
        } else {
            const bool rowok = ((unsigned)gy < IMG);
            #pragma unroll
            for (int j = 0; j < 18; ++j) {
                int gx = gx0 + j;
                bool ok = rowok && ((unsigned)gx < IMG);
                xv[j] = ok ? xr[gx] : 0.f;
                yv[j] = ok ? yr[gx] : 0.f;
            }
        }
        float ax[8]={0,0,0,0,0,0,0,0}, ay[8]={0,0,0,0,0,0,0,0};
        float axx[8]={0,0,0,0,0,0,0,0}, ayy[8]={0,0,0,0,0,0,0,0}, axy[8]={0,0,0,0,0,0,0,0};
        #pragma unroll
        for (int j = 0; j < 18; ++j) {
            float xs = xv[j], ys = yv[j];
            float xx = xs*xs, yy = ys*ys, xy = xs*ys;
            #pragma unroll
            for (int o = 0; o < 8; ++o) {
                int k = j - o;
                if (k >= 0 && k < WIN) {
                    float wk = W.w[k];
                    ax[o]+=wk*xs; ay[o]+=wk*ys; axx[o]+=wk*xx; ayy[o]+=wk*yy; axy[o]+=wk*xy;
                }
            }
        }
        const int ob = r * SH2 + cg * 8;
        uint4 u;
        u.x=pk2(ax[0],ax[1]); u.y=pk2(ax[2],ax[3]); u.z=pk2(ax[4],ax[5]); u.w=pk2(ax[6],ax[7]);
        *(uint4*)&hb[0][ob] = u;
        u.x=pk2(ay[0],ay[1]); u.y=pk2(ay[2],ay[3]); u.z=pk2(ay[4],ay[5]); u.w=pk2(ay[6],ay[7]);
        *(uint4*)&hb[1][ob] = u;
        u.x=pk2(axx[0],axx[1]); u.y=pk2(axx[2],axx[3]); u.z=pk2(axx[4],axx[5]); u.w=pk2(axx[6],axx[7]);
        *(uint4*)&hb[2][ob] = u;
        u.x=pk2(ayy[0],ayy[1]); u.y=pk2(ayy[2],ayy[3]); u.z=pk2(ayy[4],ayy[5]); u.w=pk2(ayy[6],ayy[7]);
        *(uint4*)&hb[3][ob] = u;
        u.x=pk2(axy[0],axy[1]); u.y=pk2(axy[2],axy[3]); u.z=pk2(axy[4],axy[5]); u.w=pk2(axy[6],axy[7]);
        *(uint4*)&hb[4][ob] = u;
    }
    __syncthreads();

    const int c2 = tid & 31;
    const int r0 = (tid >> 5) << 1;
    const int hbase = 2 * c2;
    h2 w2[WIN];
    #pragma unroll
    for (int k = 0; k < WIN; ++k) { f16 wk = (f16)W.w[k]; w2[k] = (h2){wk, wk}; }
    h2 acc[5][2];
    #pragma unroll
    for (int f = 0; f < 5; ++f) { acc[f][0]=(h2){(f16)0,(f16)0}; acc[f][1]=(h2){(f16)0,(f16)0}; }
    #pragma unroll
    for (int f = 0; f < 5; ++f) {
        const f16* buf = hb[f];
        h2 v[12];
        #pragma unroll
        for (int k = 0; k < 12; ++k) v[k] = *(const h2*)&buf[(r0 + k) * SH2 + hbase];
        #pragma unroll
        for (int k = 0; k < WIN; ++k) { acc[f][0] += w2[k]*v[k]; acc[f][1] += w2[k]*v[k+1]; }
    }
    const float C1 = 0.01f * 0.01f;
    const float C2 = 0.03f * 0.03f;
    float local = 0.f;
    #pragma unroll
    for (int o = 0; o < 2; ++o)
        #pragma unroll
        for (int h = 0; h < 2; ++h) {
            float mux=(float)acc[0][o][h], muy=(float)acc[1][o][h];
            float exx=(float)acc[2][o][h], eyy=(float)acc[3][o][h], exy=(float)acc[4][o][h];
            float mux2=mux*mux, muy2=muy*muy, muxy=mux*muy;
            float num=(2.f*muxy+C1)*(2.f*(exy-muxy)+C2);
            float den=(mux2+muy2+C1)*((exx-mux2)+(eyy-muy2)+C2);
            local += num * __builtin_amdgcn_rcpf(den + 1e-8f);
        }
    #pragma unroll
    for (int off = 32; off > 0; off >>= 1) local += __shfl_down(local, off, 64);
    if ((tid & 63) == 0) wsum[tid >> 6] = local;
    __syncthreads();
    if (tid == 0) atomicAdd(out_acc, wsum[0]+wsum[1]+wsum[2]+wsum[3]);
}

extern "C" void kernel_launch(void* const* d_in, const int* in_sizes, int n_in,
                              void* d_out, int out_size, void* d_ws, size_t ws_size,
                              hipStream_t stream) {
    const float* x = (const float*)d_in[0];
    const float* y = (const float*)d_in[1];
    float* out = (float*)d_out;

    GaussW gw;
    double g[WIN], s = 0.0;
    for (int i = 0; i < WIN; ++i) {
        double d = (double)(i - WIN / 2);
        g[i] = exp(-(d * d) / (2.0 * 1.5 * 1.5));
        s += g[i];
    }
    for (int i = 0; i < WIN; ++i) gw.w[i] = (float)(g[i] / s);

    // per image: 512 rows * 256 col-pairs * 16 B = 2 MB; + 24 KB partials
    auto need = [](int n) { return (size_t)n * IMG * CPR * sizeof(uint4); };
    int chunk = NIMG;                       // 48 -> 24 -> 12 -> 6 -> 3
    while (chunk > 3 && need(chunk) + NPART * 4 > ws_size) chunk >>= 1;

    if (need(chunk) + NPART * 4 <= ws_size) {
        uint4* ws      = (uint4*)d_ws;
        float* partial = (float*)((char*)d_ws + need(chunk));
        for (int off = 0; off < NIMG; off += chunk) {
            hipLaunchKernelGGL(k1_hblur, dim3(1, IMG/2, chunk), dim3(256), 0, stream,
                               x, y, ws, off, gw);
            hipLaunchKernelGGL(k2_vblur, dim3(chunk, IMG/4, 1), dim3(256), 0, stream,
                               ws, partial, off, gw);
        }
        hipLaunchKernelGGL(reduce_kernel, dim3(1), dim3(256), 0, stream, partial, out);
    } else {
        hipLaunchKernelGGL(zero_kernel, dim3(1), dim3(64), 0, stream, out);
        hipLaunchKernelGGL(fb_tile_kernel, dim3(IMG/TW, IMG/TH, NIMG), dim3(256),
                           0, stream, x, y, out, gw);
        hipLaunchKernelGGL(finish_kernel, dim3(1), dim3(64), 0, stream, out);
    }
}